// Round 16
// baseline (291.799 us; speedup 1.0000x reference)
//
#include <hip/hip_runtime.h>

#define DD 128
#define NB 8
#define KTOT 1152   // 1024 (agg: k = kk*8 + b) + 128 (self-loop h)

typedef unsigned int uint_t;
typedef __attribute__((ext_vector_type(8))) _Float16 half8v;
typedef __attribute__((ext_vector_type(2))) _Float16 half2v;
typedef __attribute__((ext_vector_type(4))) float f32x4;

static __device__ __forceinline__ half2v bc_h2(uint_t u)
{
  union { uint_t u; half2v h; } c; c.u = u; return c.h;
}

static __device__ __forceinline__ float fdot2(uint_t a, uint_t b, float acc)
{
#if __has_builtin(__builtin_amdgcn_fdot2)
  return __builtin_amdgcn_fdot2(bc_h2(a), bc_h2(b), acc, false);
#else
  half2v x = bc_h2(a), y = bc_h2(b);
  return acc + (float)x[0] * (float)y[0] + (float)x[1] * (float)y[1];
#endif
}

// ---------------------------------------------------------------------------
// WcA[layer][ks][feat][j] = W[feat][k=ks*32+j]   (A-fragment-coalesced layout)
//   k<1024 -> bases[b=k&7][kk=k>>3][feat]; else loop_w[k-1024][feat]
// ---------------------------------------------------------------------------
__global__ __launch_bounds__(256) void k_prep_w(
    const float* __restrict__ bases1, const float* __restrict__ loopw1,
    const float* __restrict__ bases2, const float* __restrict__ loopw2,
    _Float16* __restrict__ WcA)
{
  int i = blockIdx.x * 256 + threadIdx.x;          // 2*36*128*32
  if (i >= 2 * 36 * DD * 32) return;
  int layer = i / (36 * DD * 32);
  int rem   = i % (36 * DD * 32);
  int ks    = rem / (DD * 32);
  int rem2  = rem % (DD * 32);
  int feat  = rem2 / 32;
  int j     = rem2 % 32;
  int k     = ks * 32 + j;
  const float* basesL = layer ? bases2 : bases1;
  const float* loopwL = layer ? loopw2 : loopw1;
  float v;
  if (k < 1024) {
    int kk = k >> 3, b = k & 7;
    v = basesL[((size_t)b * DD + kk) * DD + feat];
  } else {
    v = loopwL[(size_t)(k - 1024) * DD + feat];
  }
  WcA[i] = (_Float16)v;
}

// cast h (fp32, ids indirection) -> fp16 [N][128]
__global__ __launch_bounds__(256) void k_cast(
    const float* __restrict__ h, const int* __restrict__ ids,
    _Float16* __restrict__ hf, int N)
{
  int i = blockIdx.x * 256 + threadIdx.x;
  if (i >= N * (DD / 8)) return;
  int n  = i / (DD / 8);
  int k8 = (i % (DD / 8)) * 8;
  int row = ids ? ids[n] : n;
  const float* hp = h + (size_t)row * DD + k8;
  float4 v0 = *(const float4*)hp;
  float4 v1 = *(const float4*)(hp + 4);
  union { _Float16 e[8]; uint4 q; } p;
  p.e[0]=(_Float16)v0.x; p.e[1]=(_Float16)v0.y; p.e[2]=(_Float16)v0.z; p.e[3]=(_Float16)v0.w;
  p.e[4]=(_Float16)v1.x; p.e[5]=(_Float16)v1.y; p.e[6]=(_Float16)v1.z; p.e[7]=(_Float16)v1.w;
  *(uint4*)&hf[(size_t)n * DD + k8] = p.q;
}

// ------------------------------- CSR by dst --------------------------------
// Segments padded to EVEN length; pad slots carry zero coefficients.
__global__ __launch_bounds__(256) void k_zero(int* __restrict__ p, int n)
{
  int i = blockIdx.x * 256 + threadIdx.x;
  if (i < n) p[i] = 0;
}

__global__ __launch_bounds__(256) void k_hist(
    const int* __restrict__ dst, int* __restrict__ cnt, int E)
{
  int e = blockIdx.x * 256 + threadIdx.x;
  if (e < E) atomicAdd(&cnt[dst[e]], 1);
}

__global__ __launch_bounds__(256) void k_bsum(
    const int* __restrict__ cnt, int* __restrict__ bsum, int N)
{
  __shared__ int s[256];
  int i = blockIdx.x * 256 + threadIdx.x;
  s[threadIdx.x] = (i < N) ? ((cnt[i] + 1) & ~1) : 0;   // padded counts
  __syncthreads();
  for (int off = 128; off > 0; off >>= 1) {
    if (threadIdx.x < off) s[threadIdx.x] += s[threadIdx.x + off];
    __syncthreads();
  }
  if (threadIdx.x == 0) bsum[blockIdx.x] = s[0];
}

__global__ __launch_bounds__(256) void k_scanb(
    const int* __restrict__ bsum, int* __restrict__ boff, int nb)
{
  __shared__ int s[256];
  int t = threadIdx.x;
  int own = (t < nb) ? bsum[t] : 0;
  s[t] = own;
  __syncthreads();
  for (int off = 1; off < 256; off <<= 1) {
    int v = (t >= off) ? s[t - off] : 0;
    __syncthreads();
    s[t] += v;
    __syncthreads();
  }
  if (t < nb) boff[t] = s[t] - own;     // exclusive
}

// scan + write row_start; ALSO write the (at most one) pad slot per node
// (psrc[rowst+cnt] = 0; its coefficients are zero because en is zeroed).
__global__ __launch_bounds__(256) void k_scan3(
    const int* __restrict__ cnt, const int* __restrict__ boff,
    int* __restrict__ row_start, int* __restrict__ psrc, int N)
{
  __shared__ int s[256];
  int t = threadIdx.x;
  int i = blockIdx.x * 256 + t;
  int c = (i < N) ? cnt[i] : 0;
  int v = (c + 1) & ~1;                                 // padded count
  s[t] = v;
  __syncthreads();
  for (int off = 1; off < 256; off <<= 1) {
    int u = (t >= off) ? s[t - off] : 0;
    __syncthreads();
    s[t] += u;
    __syncthreads();
  }
  if (i < N) {
    int rs = boff[blockIdx.x] + s[t] - v;
    row_start[i] = rs;
    if (c & 1) psrc[rs + c] = 0;                        // pad slot
  }
}

// ---------------------------------------------------------------------------
// Place + payload scatter: slot <- (src, {etype,norm}).  Scattered STORES.
// ---------------------------------------------------------------------------
__global__ __launch_bounds__(256) void k_place(
    const int* __restrict__ dst, const int* __restrict__ src,
    const int* __restrict__ etype, const float* __restrict__ norm,
    const int* __restrict__ row_start, int* __restrict__ cursor,
    int* __restrict__ psrc, int2* __restrict__ en, int E)
{
  int e = blockIdx.x * 256 + threadIdx.x;
  if (e < E) {
    int v = dst[e];
    int slot = row_start[v] + atomicAdd(&cursor[v], 1);
    psrc[slot] = src[e];
    en[slot] = make_int2(etype[e], __float_as_int(norm[e]));
  }
}

// ---------------------------------------------------------------------------
// Payload, one thread per slot PAIR: read en linearly, write pair-interleaved
// fp16 coefficients c[pair][b][parity] (32B contiguous per layer).
// en MUST be fully zero-initialized (trailing/pad pairs -> zero coeffs).
// ---------------------------------------------------------------------------
__global__ __launch_bounds__(256) void k_payload_pair(
    const int2* __restrict__ en,
    const float* __restrict__ wcomp1, const float* __restrict__ wcomp2,
    _Float16* __restrict__ c1, _Float16* __restrict__ c2, int npair)
{
  int i = blockIdx.x * 256 + threadIdx.x;
  if (i >= npair) return;
  int2 e0 = en[2 * i], e1 = en[2 * i + 1];
  float n0 = __int_as_float(e0.y), n1 = __int_as_float(e1.y);
  const float* w10 = wcomp1 + e0.x * NB;
  const float* w11 = wcomp1 + e1.x * NB;
  const float* w20 = wcomp2 + e0.x * NB;
  const float* w21 = wcomp2 + e1.x * NB;

  union { _Float16 h[16]; uint4 q[2]; } p;
  #pragma unroll
  for (int b = 0; b < NB; b++) {
    p.h[b * 2]     = (_Float16)(w10[b] * n0);
    p.h[b * 2 + 1] = (_Float16)(w11[b] * n1);
  }
  *(uint4*)&c1[(size_t)i * 16]     = p.q[0];
  *(uint4*)&c1[(size_t)i * 16 + 8] = p.q[1];
  #pragma unroll
  for (int b = 0; b < NB; b++) {
    p.h[b * 2]     = (_Float16)(w20[b] * n0);
    p.h[b * 2 + 1] = (_Float16)(w21[b] * n1);
  }
  *(uint4*)&c2[(size_t)i * 16]     = p.q[0];
  *(uint4*)&c2[(size_t)i * 16 + 8] = p.q[1];
}

// ---------------------------------------------------------------------------
// FUSED aggregate + GEMM per 16-node tile.  4 waves, 36 KB LDS -> 4 blocks/CU.
//
// LDS B-panel: 144 chunks x 16 slots x 16B  (chunk c = t*8+ksl encodes
// k = t*64 + ksl*8 + j; slot holds node, ROTATED: slot = (node + c) & 15
// to balance the write banks; read applies the same rotation).
//
// Phase 1: wave wv aggregates nodes r = wv,wv+4,wv+8,wv+12 with the fdot2
// edge-pair loop; lane owns k in [16*lane, 16*lane+16) == chunks 2*lane,
// 2*lane+1 -> two 16B LDS writes/node; self-loop h row -> 4B write to
// chunks 128..143.  One __syncthreads().
// Phase 2: 36 K-steps of {2 WcA loads (L2-hot) + 1 ds_read + 2 MFMA},
// barrier-free; wave wv covers feats [wv*32, wv*32+32) over all 16 nodes.
// LAYER==1: relu -> fp16 outh.  LAYER==2: fp32 outf (+bias).
// ---------------------------------------------------------------------------
template <int LAYER>
__global__ __launch_bounds__(256) void k_fused(
    const int* __restrict__ rowst, const int* __restrict__ cnt,
    const int* __restrict__ psrc, const _Float16* __restrict__ cpair,
    const _Float16* __restrict__ hf,     // [N][128] layer input
    const _Float16* __restrict__ WcA,    // [36][128][32]
    const float* __restrict__ bias,
    float* __restrict__ outf, _Float16* __restrict__ outh, int N)
{
  __shared__ _Float16 sB[144 * 16 * 8];   // 36 KB

  const int n0   = blockIdx.x * 16;
  const int wv   = threadIdx.x >> 6;
  const int lane = threadIdx.x & 63;
  const int l15  = lane & 15, l4 = lane >> 4;
  const uint_t* hf32 = (const uint_t*)hf;

  // ---------------- phase 1: aggregate 4 nodes/wave into LDS ----------------
  for (int r = wv; r < 16; r += 4) {
    int v = n0 + r;
    if (v >= N) continue;    // absent node -> garbage col, C-write guarded
    const int beg = rowst[v];
    const int npairs = (cnt[v] + 1) >> 1;
    const uint_t* cp = (const uint_t*)cpair + (size_t)(beg >> 1) * 8;
    const int* ps = psrc + beg;

    float ax[NB] = {}, ay[NB] = {};
    int i = 0;
    for (; i + 4 <= npairs; i += 4) {
      uint_t u[8], lo[4], hi[4];
      #pragma unroll
      for (int q = 0; q < 8; q++)
        u[q] = hf32[(size_t)ps[2*i + q] * 64 + lane];
      #pragma unroll
      for (int q = 0; q < 4; q++) {
        lo[q] = __builtin_amdgcn_perm(u[2*q], u[2*q+1], 0x01000504);
        hi[q] = __builtin_amdgcn_perm(u[2*q], u[2*q+1], 0x03020706);
      }
      #pragma unroll
      for (int b = 0; b < NB; b++) {
        #pragma unroll
        for (int q = 0; q < 4; q++) {
          uint_t cc = cp[(size_t)(i + q) * 8 + b];
          ax[b] = fdot2(cc, lo[q], ax[b]);
          ay[b] = fdot2(cc, hi[q], ay[b]);
        }
      }
    }
    for (; i + 2 <= npairs; i += 2) {
      uint_t u0 = hf32[(size_t)ps[2*i + 0] * 64 + lane];
      uint_t u1 = hf32[(size_t)ps[2*i + 1] * 64 + lane];
      uint_t u2 = hf32[(size_t)ps[2*i + 2] * 64 + lane];
      uint_t u3 = hf32[(size_t)ps[2*i + 3] * 64 + lane];
      uint_t lo01 = __builtin_amdgcn_perm(u0, u1, 0x01000504);
      uint_t hi01 = __builtin_amdgcn_perm(u0, u1, 0x03020706);
      uint_t lo23 = __builtin_amdgcn_perm(u2, u3, 0x01000504);
      uint_t hi23 = __builtin_amdgcn_perm(u2, u3, 0x03020706);
      #pragma unroll
      for (int b = 0; b < NB; b++) {
        uint_t ca = cp[(size_t)i * 8 + b];
        uint_t cb = cp[(size_t)(i + 1) * 8 + b];
        ax[b] = fdot2(ca, lo01, ax[b]);
        ay[b] = fdot2(ca, hi01, ay[b]);
        ax[b] = fdot2(cb, lo23, ax[b]);
        ay[b] = fdot2(cb, hi23, ay[b]);
      }
    }
    if (i < npairs) {
      uint_t u0 = hf32[(size_t)ps[2*i + 0] * 64 + lane];
      uint_t u1 = hf32[(size_t)ps[2*i + 1] * 64 + lane];
      uint_t lo01 = __builtin_amdgcn_perm(u0, u1, 0x01000504);
      uint_t hi01 = __builtin_amdgcn_perm(u0, u1, 0x03020706);
      #pragma unroll
      for (int b = 0; b < NB; b++) {
        uint_t ca = cp[(size_t)i * 8 + b];
        ax[b] = fdot2(ca, lo01, ax[b]);
        ay[b] = fdot2(ca, hi01, ay[b]);
      }
    }

    // write agg: chunks c0=2*lane (k=16*lane..+8), c1=2*lane+1 (+8..+16)
    union { _Float16 e[8]; uint4 q; } p0, p1;
    #pragma unroll
    for (int b = 0; b < NB; b++) { p0.e[b] = (_Float16)ax[b]; p1.e[b] = (_Float16)ay[b]; }
    int c0 = 2 * lane, c1 = 2 * lane + 1;
    *(uint4*)&sB[(c0 * 16 + ((r + c0) & 15)) * 8] = p0.q;
    *(uint4*)&sB[(c1 * 16 + ((r + c1) & 15)) * 8] = p1.q;
    // self-loop h row: lane holds halves p=2*lane,2*lane+1 -> chunk 128..143
    uint_t hv = hf32[(size_t)v * 64 + lane];
    int ch = 128 + (lane >> 5) * 8 + ((lane & 31) >> 2);
    int jb = ((2 * lane) & 7) * 2;                 // byte offset in 16B slot
    *(uint_t*)((char*)sB + (ch * 16 + ((r + ch) & 15)) * 16 + jb) = hv;
  }
  __syncthreads();

  // ---------------- phase 2: MFMA from LDS, barrier-free ----------------
  f32x4 acc[2];
  acc[0] = (f32x4)0.f; acc[1] = (f32x4)0.f;
  const int fbase = wv * 32 + l15;
  const int koff  = l4 * 8;

  #pragma unroll 6
  for (int ks = 0; ks < 36; ks++) {
    half8v af0 = *(const half8v*)&WcA[((size_t)ks * DD + fbase     ) * 32 + koff];
    half8v af1 = *(const half8v*)&WcA[((size_t)ks * DD + fbase + 16) * 32 + koff];
    int c = (ks >> 1) * 8 + (ks & 1) * 4 + l4;
    half8v bf = *(const half8v*)&sB[(c * 16 + ((l15 + c) & 15)) * 8];
    acc[0] = __builtin_amdgcn_mfma_f32_16x16x32_f16(af0, bf, acc[0], 0, 0, 0);
    acc[1] = __builtin_amdgcn_mfma_f32_16x16x32_f16(af1, bf, acc[1], 0, 0, 0);
  }

  // C layout: col(=node) = lane&15, row(=feat) = l4*4 + rr
  int n = n0 + l15;
  if (n < N) {
    #pragma unroll
    for (int mf = 0; mf < 2; mf++) {
      int feat = wv * 32 + mf * 16 + l4 * 4;
      if (LAYER == 1) {
        union { _Float16 e[4]; uint2 q; } p;
        #pragma unroll
        for (int rr = 0; rr < 4; rr++)
          p.e[rr] = (_Float16)fmaxf(acc[mf][rr] + bias[feat + rr], 0.f);
        *(uint2*)&outh[(size_t)n * DD + feat] = p.q;
      } else {
        float4 o;
        o.x = acc[mf][0] + bias[feat + 0];
        o.y = acc[mf][1] + bias[feat + 1];
        o.z = acc[mf][2] + bias[feat + 2];
        o.w = acc[mf][3] + bias[feat + 3];
        *(float4*)&outf[(size_t)n * DD + feat] = o;
      }
    }
  }
}

extern "C" void kernel_launch(void* const* d_in, const int* in_sizes, int n_in,
                              void* d_out, int out_size, void* d_ws, size_t ws_size,
                              hipStream_t stream)
{
  const int*   h_ids     = (const int*)d_in[0];
  const int*   src       = (const int*)d_in[1];
  const int*   dst       = (const int*)d_in[2];
  const int*   etype     = (const int*)d_in[3];
  const float* norm      = (const float*)d_in[4];
  const float* embedding = (const float*)d_in[5];
  const float* w_comp1   = (const float*)d_in[6];
  const float* bases1    = (const float*)d_in[7];
  const float* loop_w1   = (const float*)d_in[8];
  const float* bias1     = (const float*)d_in[9];
  const float* w_comp2   = (const float*)d_in[10];
  const float* bases2    = (const float*)d_in[11];
  const float* loop_w2   = (const float*)d_in[12];
  const float* bias2     = (const float*)d_in[13];

  const int N = in_sizes[0];
  const int E = in_sizes[1];
  const int S = (E + N) & ~1;           // padded-slot capacity (even)
  const int NPAIR = S >> 1;
  const int NBLK = (N + 255) / 256;     // <= 256 (N <= 65536)

  // ---- workspace carve-up (256B aligned) ----
  char* base = (char*)d_ws;
  size_t off = 0;
  auto alloc = [&](size_t bytes) -> char* {
    char* p = base + off;
    off += (bytes + 255) & ~(size_t)255;
    return p;
  };
  _Float16* hfp  = (_Float16*)alloc((size_t)N * DD * 2);     // 12.8 MB
  _Float16* h1h  = (_Float16*)alloc((size_t)N * DD * 2);     // 12.8 MB
  _Float16* WcA  = (_Float16*)alloc((size_t)2 * 36 * DD * 32 * 2);
  int*      cnt    = (int*)   alloc((size_t)2 * N * 4);      // cnt + cursor
  int*      cursor = cnt + N;
  int2*     en     = (int2*)  alloc((size_t)S * 8);          // directly after cnt
  int*      rowst  = (int*)   alloc((size_t)N * 4);
  int*      bsum   = (int*)   alloc(256 * 4);
  int*      boff   = (int*)   alloc(256 * 4);
  int*      psrc   = (int*)   alloc((size_t)S * 4);
  _Float16* c1     = (_Float16*)alloc((size_t)S * 8 * 2);    // ~10.4 MB
  _Float16* c2     = (_Float16*)alloc((size_t)S * 8 * 2);    // ~10.4 MB
  float*    out    = (float*)d_out;

  // ---- build padded CSR by dst (reused by both layers) ----
  // fused zero: cnt+cursor (2N ints) .. en (2S ints) are contiguous
  int zn = (int)(((char*)(en + S) - (char*)cnt) / 4);
  k_zero <<<(zn + 255) / 256, 256, 0, stream>>>(cnt, zn);
  k_hist <<<(E + 255) / 256, 256, 0, stream>>>(dst, cnt, E);
  k_bsum <<<NBLK, 256, 0, stream>>>(cnt, bsum, N);
  k_scanb<<<1, 256, 0, stream>>>(bsum, boff, NBLK);
  k_scan3<<<NBLK, 256, 0, stream>>>(cnt, boff, rowst, psrc, N);
  k_place<<<(E + 255) / 256, 256, 0, stream>>>(dst, src, etype, norm,
                                               rowst, cursor, psrc, en, E);
  k_payload_pair<<<(NPAIR + 255) / 256, 256, 0, stream>>>(
      en, w_comp1, w_comp2, c1, c2, NPAIR);

  // ---- weights -> fp16 A-coalesced layout ----
  k_prep_w<<<(2 * 36 * DD * 32 + 255) / 256, 256, 0, stream>>>(bases1, loop_w1, bases2, loop_w2, WcA);

  dim3 gf((N + 15) / 16);

  // ---- layer 1 ----
  k_cast<<<(N * (DD / 8) + 255) / 256, 256, 0, stream>>>(embedding, h_ids, hfp, N);
  k_fused<1><<<gf, 256, 0, stream>>>(rowst, cnt, psrc, c1, hfp, WcA, bias1,
                                     nullptr, h1h, N);
  // ---- layer 2 ----
  k_fused<2><<<gf, 256, 0, stream>>>(rowst, cnt, psrc, c2, h1h,
                                     WcA + (size_t)36 * DD * 32, bias2, out, nullptr, N);
}

// Round 17
// 255.735 us; speedup vs baseline: 1.1410x; 1.1410x over previous
//
#include <hip/hip_runtime.h>

#define DD 128
#define NB 8
#define KTOT 1152   // 1024 (agg: k = kk*8 + b) + 128 (self-loop h)

typedef unsigned int uint_t;
typedef __attribute__((ext_vector_type(8))) _Float16 half8v;
typedef __attribute__((ext_vector_type(2))) _Float16 half2v;
typedef __attribute__((ext_vector_type(4))) float f32x4;

static __device__ __forceinline__ void gld_lds16(const _Float16* g, _Float16* l)
{
  __builtin_amdgcn_global_load_lds(
      (const __attribute__((address_space(1))) void*)g,
      (__attribute__((address_space(3))) void*)l, 16, 0, 0);
}

static __device__ __forceinline__ half2v bc_h2(uint_t u)
{
  union { uint_t u; half2v h; } c; c.u = u; return c.h;
}

static __device__ __forceinline__ float fdot2(uint_t a, uint_t b, float acc)
{
#if __has_builtin(__builtin_amdgcn_fdot2)
  return __builtin_amdgcn_fdot2(bc_h2(a), bc_h2(b), acc, false);
#else
  half2v x = bc_h2(a), y = bc_h2(b);
  return acc + (float)x[0] * (float)y[0] + (float)x[1] * (float)y[1];
#endif
}

// ---------------------------------------------------------------------------
// WcA[layer][ks][feat][j] = W[feat][k=ks*32+j]   (A-fragment-coalesced layout)
//   k<1024 -> bases[b=k&7][kk=k>>3][feat]; else loop_w[k-1024][feat]
// ---------------------------------------------------------------------------
__global__ __launch_bounds__(256) void k_prep_w(
    const float* __restrict__ bases1, const float* __restrict__ loopw1,
    const float* __restrict__ bases2, const float* __restrict__ loopw2,
    _Float16* __restrict__ WcA)
{
  int i = blockIdx.x * 256 + threadIdx.x;          // 2*36*128*32
  if (i >= 2 * 36 * DD * 32) return;
  int layer = i / (36 * DD * 32);
  int rem   = i % (36 * DD * 32);
  int ks    = rem / (DD * 32);
  int rem2  = rem % (DD * 32);
  int feat  = rem2 / 32;
  int j     = rem2 % 32;
  int k     = ks * 32 + j;
  const float* basesL = layer ? bases2 : bases1;
  const float* loopwL = layer ? loopw2 : loopw1;
  float v;
  if (k < 1024) {
    int kk = k >> 3, b = k & 7;
    v = basesL[((size_t)b * DD + kk) * DD + feat];
  } else {
    v = loopwL[(size_t)(k - 1024) * DD + feat];
  }
  WcA[i] = (_Float16)v;
}

// cast h (fp32, ids indirection) -> fp16 [N][128]
__global__ __launch_bounds__(256) void k_cast(
    const float* __restrict__ h, const int* __restrict__ ids,
    _Float16* __restrict__ hf, int N)
{
  int i = blockIdx.x * 256 + threadIdx.x;
  if (i >= N * (DD / 8)) return;
  int n  = i / (DD / 8);
  int k8 = (i % (DD / 8)) * 8;
  int row = ids ? ids[n] : n;
  const float* hp = h + (size_t)row * DD + k8;
  float4 v0 = *(const float4*)hp;
  float4 v1 = *(const float4*)(hp + 4);
  union { _Float16 e[8]; uint4 q; } p;
  p.e[0]=(_Float16)v0.x; p.e[1]=(_Float16)v0.y; p.e[2]=(_Float16)v0.z; p.e[3]=(_Float16)v0.w;
  p.e[4]=(_Float16)v1.x; p.e[5]=(_Float16)v1.y; p.e[6]=(_Float16)v1.z; p.e[7]=(_Float16)v1.w;
  *(uint4*)&hf[(size_t)n * DD + k8] = p.q;
}

// ------------------------------- CSR by dst --------------------------------
// Segments padded to EVEN length; pad slots carry zero coefficients.
__global__ __launch_bounds__(256) void k_zero(int* __restrict__ p, int n)
{
  int i = blockIdx.x * 256 + threadIdx.x;
  if (i < n) p[i] = 0;
}

// histogram AND capture each edge's within-segment slot (atomic's return)
__global__ __launch_bounds__(256) void k_hist(
    const int* __restrict__ dst, int* __restrict__ cnt,
    int* __restrict__ slotin, int E)
{
  int e = blockIdx.x * 256 + threadIdx.x;
  if (e < E) slotin[e] = atomicAdd(&cnt[dst[e]], 1);
}

__global__ __launch_bounds__(256) void k_bsum(
    const int* __restrict__ cnt, int* __restrict__ bsum, int N)
{
  __shared__ int s[256];
  int i = blockIdx.x * 256 + threadIdx.x;
  s[threadIdx.x] = (i < N) ? ((cnt[i] + 1) & ~1) : 0;   // padded counts
  __syncthreads();
  for (int off = 128; off > 0; off >>= 1) {
    if (threadIdx.x < off) s[threadIdx.x] += s[threadIdx.x + off];
    __syncthreads();
  }
  if (threadIdx.x == 0) bsum[blockIdx.x] = s[0];
}

__global__ __launch_bounds__(256) void k_scanb(
    const int* __restrict__ bsum, int* __restrict__ boff, int nb)
{
  __shared__ int s[256];
  int t = threadIdx.x;
  int own = (t < nb) ? bsum[t] : 0;
  s[t] = own;
  __syncthreads();
  for (int off = 1; off < 256; off <<= 1) {
    int v = (t >= off) ? s[t - off] : 0;
    __syncthreads();
    s[t] += v;
    __syncthreads();
  }
  if (t < nb) boff[t] = s[t] - own;     // exclusive
}

// scan + write row_start; ALSO write the (at most one) pad slot per node
// (psrc[rowst+cnt] = 0; its coefficients are zero because en is zeroed).
__global__ __launch_bounds__(256) void k_scan3(
    const int* __restrict__ cnt, const int* __restrict__ boff,
    int* __restrict__ row_start, int* __restrict__ psrc, int N)
{
  __shared__ int s[256];
  int t = threadIdx.x;
  int i = blockIdx.x * 256 + t;
  int c = (i < N) ? cnt[i] : 0;
  int v = (c + 1) & ~1;                                 // padded count
  s[t] = v;
  __syncthreads();
  for (int off = 1; off < 256; off <<= 1) {
    int u = (t >= off) ? s[t - off] : 0;
    __syncthreads();
    s[t] += u;
    __syncthreads();
  }
  if (i < N) {
    int rs = boff[blockIdx.x] + s[t] - v;
    row_start[i] = rs;
    if (c & 1) psrc[rs + c] = 0;                        // pad slot
  }
}

// ---------------------------------------------------------------------------
// Place: ATOMIC-FREE.  slot = rowst[dst[e]] + slotin[e] (captured in k_hist).
// Linear reads + 2 scattered fire-and-forget stores per edge.
// ---------------------------------------------------------------------------
__global__ __launch_bounds__(256) void k_place(
    const int* __restrict__ dst, const int* __restrict__ src,
    const int* __restrict__ etype, const float* __restrict__ norm,
    const int* __restrict__ row_start, const int* __restrict__ slotin,
    int* __restrict__ psrc, int2* __restrict__ en, int E)
{
  int e = blockIdx.x * 256 + threadIdx.x;
  if (e < E) {
    int slot = row_start[dst[e]] + slotin[e];
    psrc[slot] = src[e];
    en[slot] = make_int2(etype[e], __float_as_int(norm[e]));
  }
}

// ---------------------------------------------------------------------------
// Payload, one thread per slot PAIR: read en linearly, write pair-interleaved
// fp16 coefficients c[pair][b][parity] (32B contiguous per layer).
// en MUST be fully zero-initialized (trailing/pad pairs -> zero coeffs).
// ---------------------------------------------------------------------------
__global__ __launch_bounds__(256) void k_payload_pair(
    const int2* __restrict__ en,
    const float* __restrict__ wcomp1, const float* __restrict__ wcomp2,
    _Float16* __restrict__ c1, _Float16* __restrict__ c2, int npair)
{
  int i = blockIdx.x * 256 + threadIdx.x;
  if (i >= npair) return;
  int2 e0 = en[2 * i], e1 = en[2 * i + 1];
  float n0 = __int_as_float(e0.y), n1 = __int_as_float(e1.y);
  const float* w10 = wcomp1 + e0.x * NB;
  const float* w11 = wcomp1 + e1.x * NB;
  const float* w20 = wcomp2 + e0.x * NB;
  const float* w21 = wcomp2 + e1.x * NB;

  union { _Float16 h[16]; uint4 q[2]; } p;
  #pragma unroll
  for (int b = 0; b < NB; b++) {
    p.h[b * 2]     = (_Float16)(w10[b] * n0);
    p.h[b * 2 + 1] = (_Float16)(w11[b] * n1);
  }
  *(uint4*)&c1[(size_t)i * 16]     = p.q[0];
  *(uint4*)&c1[(size_t)i * 16 + 8] = p.q[1];
  #pragma unroll
  for (int b = 0; b < NB; b++) {
    p.h[b * 2]     = (_Float16)(w20[b] * n0);
    p.h[b * 2 + 1] = (_Float16)(w21[b] * n1);
  }
  *(uint4*)&c2[(size_t)i * 16]     = p.q[0];
  *(uint4*)&c2[(size_t)i * 16 + 8] = p.q[1];
}

// ---------------------------------------------------------------------------
// Aggregation: one wave per dst node; edge-pair inner loop with fdot2,
// 4 pairs (8 edges) in flight for deeper memory-level parallelism.
// ---------------------------------------------------------------------------
__global__ __launch_bounds__(256) void k_agg(
    const int* __restrict__ rowst, const int* __restrict__ cnt,
    const int* __restrict__ psrc, const _Float16* __restrict__ cpair,
    const _Float16* __restrict__ hf,
    _Float16* __restrict__ agg, int N)
{
  int v = blockIdx.x * 4 + (threadIdx.x >> 6);
  if (v >= N) return;
  int lane = threadIdx.x & 63;
  const uint_t* hf32 = (const uint_t*)hf;
  const int beg = rowst[v];                    // even by construction
  const int npairs = (cnt[v] + 1) >> 1;
  const uint_t* cp = (const uint_t*)cpair + (size_t)(beg >> 1) * 8;
  const int* ps = psrc + beg;

  float ax[NB] = {}, ay[NB] = {};
  int i = 0;
  for (; i + 4 <= npairs; i += 4) {
    uint_t u[8], lo[4], hi[4];
    #pragma unroll
    for (int q = 0; q < 8; q++)
      u[q] = hf32[(size_t)ps[2*i + q] * 64 + lane];
    #pragma unroll
    for (int q = 0; q < 4; q++) {
      lo[q] = __builtin_amdgcn_perm(u[2*q], u[2*q+1], 0x01000504);
      hi[q] = __builtin_amdgcn_perm(u[2*q], u[2*q+1], 0x03020706);
    }
    #pragma unroll
    for (int b = 0; b < NB; b++) {
      #pragma unroll
      for (int q = 0; q < 4; q++) {
        uint_t cc = cp[(size_t)(i + q) * 8 + b];
        ax[b] = fdot2(cc, lo[q], ax[b]);
        ay[b] = fdot2(cc, hi[q], ay[b]);
      }
    }
  }
  for (; i + 2 <= npairs; i += 2) {
    uint_t u0 = hf32[(size_t)ps[2*i + 0] * 64 + lane];
    uint_t u1 = hf32[(size_t)ps[2*i + 1] * 64 + lane];
    uint_t u2 = hf32[(size_t)ps[2*i + 2] * 64 + lane];
    uint_t u3 = hf32[(size_t)ps[2*i + 3] * 64 + lane];
    uint_t lo01 = __builtin_amdgcn_perm(u0, u1, 0x01000504);
    uint_t hi01 = __builtin_amdgcn_perm(u0, u1, 0x03020706);
    uint_t lo23 = __builtin_amdgcn_perm(u2, u3, 0x01000504);
    uint_t hi23 = __builtin_amdgcn_perm(u2, u3, 0x03020706);
    #pragma unroll
    for (int b = 0; b < NB; b++) {
      uint_t ca = cp[(size_t)i * 8 + b];
      uint_t cb = cp[(size_t)(i + 1) * 8 + b];
      ax[b] = fdot2(ca, lo01, ax[b]);
      ay[b] = fdot2(ca, hi01, ay[b]);
      ax[b] = fdot2(cb, lo23, ax[b]);
      ay[b] = fdot2(cb, hi23, ay[b]);
    }
  }
  if (i < npairs) {
    uint_t u0 = hf32[(size_t)ps[2*i + 0] * 64 + lane];
    uint_t u1 = hf32[(size_t)ps[2*i + 1] * 64 + lane];
    uint_t lo01 = __builtin_amdgcn_perm(u0, u1, 0x01000504);
    uint_t hi01 = __builtin_amdgcn_perm(u0, u1, 0x03020706);
    #pragma unroll
    for (int b = 0; b < NB; b++) {
      uint_t ca = cp[(size_t)i * 8 + b];
      ax[b] = fdot2(ca, lo01, ax[b]);
      ay[b] = fdot2(ca, hi01, ay[b]);
    }
  }

  union { _Float16 e[8]; uint4 q; } p0, p1;
  #pragma unroll
  for (int b = 0; b < NB; b++) { p0.e[b] = (_Float16)ax[b]; p1.e[b] = (_Float16)ay[b]; }
  uint4* dstp = (uint4*)&agg[(size_t)v * 1024 + lane * 16];
  dstp[0] = p0.q;
  dstp[1] = p1.q;
}

// ---------------------------------------------------------------------------
// MFMA GEMM (exact round-9 structure, best measured): K=1152, BK=64, TN=64,
// LDS-shared B with global_load_lds + plain __syncthreads double-buffer.
// LDS: 2 x 8KB, [kslot 0..7][node 0..63][16B]; wave wv stages kslots wv,wv+4.
// ---------------------------------------------------------------------------
template <int LAYER>
__global__ __launch_bounds__(256) void k_mm(
    const _Float16* __restrict__ agg,   // [N][1024]
    const _Float16* __restrict__ hf,    // [N][128]
    const _Float16* __restrict__ WcA,   // [36][128][32]
    const float* __restrict__ bias,
    float* __restrict__ outf, _Float16* __restrict__ outh, int N)
{
  __shared__ _Float16 sB[2][4096];      // 2 x 8KB

  const int n0   = blockIdx.x * 64;
  const int wv   = threadIdx.x >> 6;
  const int lane = threadIdx.x & 63;
  const int l15  = lane & 15, l4 = lane >> 4;

  int nodeL = n0 + lane; if (nodeL >= N) nodeL = N - 1;   // stage-source clamp

  f32x4 acc[2][4];
  #pragma unroll
  for (int a = 0; a < 2; a++)
    #pragma unroll
    for (int b = 0; b < 4; b++) acc[a][b] = (f32x4)0.f;

  const int fbase = wv * 32 + l15;      // + mf*16
  const int koff  = l4 * 8;

  auto STAGE = [&](int buf, int t) {
    const _Float16 *g0, *g1;
    if (t < 16) {
      g0 = &agg[(size_t)nodeL * 1024 + (2 * t)     * 32 + wv * 8];
      g1 = &agg[(size_t)nodeL * 1024 + (2 * t + 1) * 32 + wv * 8];
    } else {
      g0 = &hf[(size_t)nodeL * DD + (2 * t - 32) * 32 + wv * 8];
      g1 = &hf[(size_t)nodeL * DD + (2 * t - 31) * 32 + wv * 8];
    }
    gld_lds16(g0, &sB[buf][ wv      * 512]);
    gld_lds16(g1, &sB[buf][(wv + 4) * 512]);
  };

  auto COMPUTE = [&](int buf, int t) {
    #pragma unroll
    for (int sub = 0; sub < 2; sub++) {
      const int ks = 2 * t + sub;
      half8v af[2], bfr[4];
      #pragma unroll
      for (int mf = 0; mf < 2; mf++)
        af[mf] = *(const half8v*)&WcA[((size_t)ks * DD + fbase + mf * 16) * 32 + koff];
      #pragma unroll
      for (int nf = 0; nf < 4; nf++)
        bfr[nf] = *(const half8v*)&sB[buf][(l4 + sub * 4) * 512 + (nf * 16 + l15) * 8];
      #pragma unroll
      for (int mf = 0; mf < 2; mf++)
        #pragma unroll
        for (int nf = 0; nf < 4; nf++)
          acc[mf][nf] = __builtin_amdgcn_mfma_f32_16x16x32_f16(af[mf], bfr[nf], acc[mf][nf], 0, 0, 0);
    }
  };

  STAGE(0, 0);
  __syncthreads();
  int cur = 0;
  for (int t = 0; t < 17; t++) {
    STAGE(cur ^ 1, t + 1);
    COMPUTE(cur, t);
    __syncthreads();
    cur ^= 1;
  }
  COMPUTE(cur, 17);

  #pragma unroll
  for (int mf = 0; mf < 2; mf++)
    #pragma unroll
    for (int nf = 0; nf < 4; nf++) {
      int n = n0 + nf * 16 + l15;
      if (n >= N) continue;
      int feat = wv * 32 + mf * 16 + l4 * 4;
      if (LAYER == 1) {
        union { _Float16 e[4]; uint2 q; } p;
        #pragma unroll
        for (int r = 0; r < 4; r++)
          p.e[r] = (_Float16)fmaxf(acc[mf][nf][r] + bias[feat + r], 0.f);
        *(uint2*)&outh[(size_t)n * DD + feat] = p.q;
      } else {
        float4 o;
        o.x = acc[mf][nf][0] + bias[feat + 0];
        o.y = acc[mf][nf][1] + bias[feat + 1];
        o.z = acc[mf][nf][2] + bias[feat + 2];
        o.w = acc[mf][nf][3] + bias[feat + 3];
        *(float4*)&outf[(size_t)n * DD + feat] = o;
      }
    }
}

extern "C" void kernel_launch(void* const* d_in, const int* in_sizes, int n_in,
                              void* d_out, int out_size, void* d_ws, size_t ws_size,
                              hipStream_t stream)
{
  const int*   h_ids     = (const int*)d_in[0];
  const int*   src       = (const int*)d_in[1];
  const int*   dst       = (const int*)d_in[2];
  const int*   etype     = (const int*)d_in[3];
  const float* norm      = (const float*)d_in[4];
  const float* embedding = (const float*)d_in[5];
  const float* w_comp1   = (const float*)d_in[6];
  const float* bases1    = (const float*)d_in[7];
  const float* loop_w1   = (const float*)d_in[8];
  const float* bias1     = (const float*)d_in[9];
  const float* w_comp2   = (const float*)d_in[10];
  const float* bases2    = (const float*)d_in[11];
  const float* loop_w2   = (const float*)d_in[12];
  const float* bias2     = (const float*)d_in[13];

  const int N = in_sizes[0];
  const int E = in_sizes[1];
  const int S = (E + N) & ~1;           // padded-slot capacity (even)
  const int NPAIR = S >> 1;
  const int NBLK = (N + 255) / 256;     // <= 256 (N <= 65536)

  // ---- workspace carve-up (256B aligned) ----
  char* base = (char*)d_ws;
  size_t off = 0;
  auto alloc = [&](size_t bytes) -> char* {
    char* p = base + off;
    off += (bytes + 255) & ~(size_t)255;
    return p;
  };
  _Float16* agg  = (_Float16*)alloc((size_t)N * 1024 * 2);   // 102.4 MB
  _Float16* hfp  = (_Float16*)alloc((size_t)N * DD * 2);     // 12.8 MB
  _Float16* h1h  = (_Float16*)alloc((size_t)N * DD * 2);     // 12.8 MB
  _Float16* WcA  = (_Float16*)alloc((size_t)2 * 36 * DD * 32 * 2);
  int*      cnt    = (int*)   alloc((size_t)N * 4);          // contiguous with en
  int2*     en     = (int2*)  alloc((size_t)S * 8);
  int*      rowst  = (int*)   alloc((size_t)N * 4);
  int*      bsum   = (int*)   alloc(256 * 4);
  int*      boff   = (int*)   alloc(256 * 4);
  int*      slotin = (int*)   alloc((size_t)E * 4);
  int*      psrc   = (int*)   alloc((size_t)S * 4);
  _Float16* c1     = (_Float16*)alloc((size_t)S * 8 * 2);    // ~10.4 MB
  _Float16* c2     = (_Float16*)alloc((size_t)S * 8 * 2);    // ~10.4 MB
  float*    out    = (float*)d_out;

  // ---- build padded CSR by dst (reused by both layers) ----
  // fused zero: cnt (N ints) .. en (2S ints) are contiguous
  int zn = (int)(((char*)(en + S) - (char*)cnt) / 4);
  k_zero <<<(zn + 255) / 256, 256, 0, stream>>>(cnt, zn);
  k_hist <<<(E + 255) / 256, 256, 0, stream>>>(dst, cnt, slotin, E);
  k_bsum <<<NBLK, 256, 0, stream>>>(cnt, bsum, N);
  k_scanb<<<1, 256, 0, stream>>>(bsum, boff, NBLK);
  k_scan3<<<NBLK, 256, 0, stream>>>(cnt, boff, rowst, psrc, N);
  k_place<<<(E + 255) / 256, 256, 0, stream>>>(dst, src, etype, norm,
                                               rowst, slotin, psrc, en, E);
  k_payload_pair<<<(NPAIR + 255) / 256, 256, 0, stream>>>(
      en, w_comp1, w_comp2, c1, c2, NPAIR);

  // ---- weights -> fp16 A-coalesced layout ----
  k_prep_w<<<(2 * 36 * DD * 32 + 255) / 256, 256, 0, stream>>>(bases1, loop_w1, bases2, loop_w2, WcA);

  dim3 gmm((N + 63) / 64);
  int gagg = (N + 3) / 4;

  // ---- layer 1 ----
  k_cast<<<(N * (DD / 8) + 255) / 256, 256, 0, stream>>>(embedding, h_ids, hfp, N);
  k_agg<<<gagg, 256, 0, stream>>>(rowst, cnt, psrc, c1, hfp, agg, N);
  k_mm<1><<<gmm, 256, 0, stream>>>(agg, hfp, WcA, bias1, nullptr, h1h, N);

  // ---- layer 2 ----
  k_agg<<<gagg, 256, 0, stream>>>(rowst, cnt, psrc, c2, h1h, agg, N);
  k_mm<2><<<gmm, 256, 0, stream>>>(agg, h1h, WcA + (size_t)36 * DD * 32, bias2, out, nullptr, N);
}

// Round 18
// 244.717 us; speedup vs baseline: 1.1924x; 1.0450x over previous
//
#include <hip/hip_runtime.h>

#define DD 128
#define NB 8
#define KTOT 1152   // 1024 (agg: k = kk*8 + b) + 128 (self-loop h)

typedef unsigned int uint_t;
typedef __attribute__((ext_vector_type(8))) _Float16 half8v;
typedef __attribute__((ext_vector_type(2))) _Float16 half2v;
typedef __attribute__((ext_vector_type(4))) float f32x4;

static __device__ __forceinline__ void gld_lds16(const _Float16* g, _Float16* l)
{
  __builtin_amdgcn_global_load_lds(
      (const __attribute__((address_space(1))) void*)g,
      (__attribute__((address_space(3))) void*)l, 16, 0, 0);
}

static __device__ __forceinline__ half2v bc_h2(uint_t u)
{
  union { uint_t u; half2v h; } c; c.u = u; return c.h;
}

static __device__ __forceinline__ float fdot2(uint_t a, uint_t b, float acc)
{
#if __has_builtin(__builtin_amdgcn_fdot2)
  return __builtin_amdgcn_fdot2(bc_h2(a), bc_h2(b), acc, false);
#else
  half2v x = bc_h2(a), y = bc_h2(b);
  return acc + (float)x[0] * (float)y[0] + (float)x[1] * (float)y[1];
#endif
}

// ---------------------------------------------------------------------------
// WcA[layer][ks][feat][j] = W[feat][k=ks*32+j]   (A-fragment-coalesced layout)
//   k<1024 -> bases[b=k&7][kk=k>>3][feat]; else loop_w[k-1024][feat]
// ---------------------------------------------------------------------------
__global__ __launch_bounds__(256) void k_prep_w(
    const float* __restrict__ bases1, const float* __restrict__ loopw1,
    const float* __restrict__ bases2, const float* __restrict__ loopw2,
    _Float16* __restrict__ WcA)
{
  int i = blockIdx.x * 256 + threadIdx.x;          // 2*36*128*32
  if (i >= 2 * 36 * DD * 32) return;
  int layer = i / (36 * DD * 32);
  int rem   = i % (36 * DD * 32);
  int ks    = rem / (DD * 32);
  int rem2  = rem % (DD * 32);
  int feat  = rem2 / 32;
  int j     = rem2 % 32;
  int k     = ks * 32 + j;
  const float* basesL = layer ? bases2 : bases1;
  const float* loopwL = layer ? loopw2 : loopw1;
  float v;
  if (k < 1024) {
    int kk = k >> 3, b = k & 7;
    v = basesL[((size_t)b * DD + kk) * DD + feat];
  } else {
    v = loopwL[(size_t)(k - 1024) * DD + feat];
  }
  WcA[i] = (_Float16)v;
}

// cast h (fp32, ids indirection) -> fp16 [N][128]
__global__ __launch_bounds__(256) void k_cast(
    const float* __restrict__ h, const int* __restrict__ ids,
    _Float16* __restrict__ hf, int N)
{
  int i = blockIdx.x * 256 + threadIdx.x;
  if (i >= N * (DD / 8)) return;
  int n  = i / (DD / 8);
  int k8 = (i % (DD / 8)) * 8;
  int row = ids ? ids[n] : n;
  const float* hp = h + (size_t)row * DD + k8;
  float4 v0 = *(const float4*)hp;
  float4 v1 = *(const float4*)(hp + 4);
  union { _Float16 e[8]; uint4 q; } p;
  p.e[0]=(_Float16)v0.x; p.e[1]=(_Float16)v0.y; p.e[2]=(_Float16)v0.z; p.e[3]=(_Float16)v0.w;
  p.e[4]=(_Float16)v1.x; p.e[5]=(_Float16)v1.y; p.e[6]=(_Float16)v1.z; p.e[7]=(_Float16)v1.w;
  *(uint4*)&hf[(size_t)n * DD + k8] = p.q;
}

// ------------------------------- CSR by dst --------------------------------
// Segments padded to EVEN length; pad slots carry zero coefficients.
__global__ __launch_bounds__(256) void k_zero(int* __restrict__ p, int n)
{
  int i = blockIdx.x * 256 + threadIdx.x;
  if (i < n) p[i] = 0;
}

// histogram AND capture each edge's within-segment slot (atomic's return)
__global__ __launch_bounds__(256) void k_hist(
    const int* __restrict__ dst, int* __restrict__ cnt,
    int* __restrict__ slotin, int E)
{
  int e = blockIdx.x * 256 + threadIdx.x;
  if (e < E) slotin[e] = atomicAdd(&cnt[dst[e]], 1);
}

__global__ __launch_bounds__(256) void k_bsum(
    const int* __restrict__ cnt, int* __restrict__ bsum, int N)
{
  __shared__ int s[256];
  int i = blockIdx.x * 256 + threadIdx.x;
  s[threadIdx.x] = (i < N) ? ((cnt[i] + 1) & ~1) : 0;   // padded counts
  __syncthreads();
  for (int off = 128; off > 0; off >>= 1) {
    if (threadIdx.x < off) s[threadIdx.x] += s[threadIdx.x + off];
    __syncthreads();
  }
  if (threadIdx.x == 0) bsum[blockIdx.x] = s[0];
}

__global__ __launch_bounds__(256) void k_scanb(
    const int* __restrict__ bsum, int* __restrict__ boff, int nb)
{
  __shared__ int s[256];
  int t = threadIdx.x;
  int own = (t < nb) ? bsum[t] : 0;
  s[t] = own;
  __syncthreads();
  for (int off = 1; off < 256; off <<= 1) {
    int v = (t >= off) ? s[t - off] : 0;
    __syncthreads();
    s[t] += v;
    __syncthreads();
  }
  if (t < nb) boff[t] = s[t] - own;     // exclusive
}

__global__ __launch_bounds__(256) void k_scan3(
    const int* __restrict__ cnt, const int* __restrict__ boff,
    int* __restrict__ row_start, int N)
{
  __shared__ int s[256];
  int t = threadIdx.x;
  int i = blockIdx.x * 256 + t;
  int c = (i < N) ? cnt[i] : 0;
  int v = (c + 1) & ~1;                                 // padded count
  s[t] = v;
  __syncthreads();
  for (int off = 1; off < 256; off <<= 1) {
    int u = (t >= off) ? s[t - off] : 0;
    __syncthreads();
    s[t] += u;
    __syncthreads();
  }
  if (i < N) row_start[i] = boff[blockIdx.x] + s[t] - v;
}

// ---------------------------------------------------------------------------
// Place: ATOMIC-FREE, ONE 16B scattered store per edge:
// en4[slot] = {src, etype, norm_bits, 0}.  en4 pre-zeroed -> pad/trailing
// slots decode as src=0, etype=0, norm=0 (zero contribution).
// ---------------------------------------------------------------------------
__global__ __launch_bounds__(256) void k_place(
    const int* __restrict__ dst, const int* __restrict__ src,
    const int* __restrict__ etype, const float* __restrict__ norm,
    const int* __restrict__ row_start, const int* __restrict__ slotin,
    int4* __restrict__ en4, int E)
{
  int e = blockIdx.x * 256 + threadIdx.x;
  if (e < E) {
    int slot = row_start[dst[e]] + slotin[e];
    en4[slot] = make_int4(src[e], etype[e], __float_as_int(norm[e]), 0);
  }
}

// ---------------------------------------------------------------------------
// Payload, one thread per slot PAIR: read en4 linearly, write psrc (8B) and
// pair-interleaved fp16 coefficients c[pair][b][parity] (32B per layer).
// ---------------------------------------------------------------------------
__global__ __launch_bounds__(256) void k_payload_pair(
    const int4* __restrict__ en4,
    const float* __restrict__ wcomp1, const float* __restrict__ wcomp2,
    int* __restrict__ psrc,
    _Float16* __restrict__ c1, _Float16* __restrict__ c2, int npair)
{
  int i = blockIdx.x * 256 + threadIdx.x;
  if (i >= npair) return;
  int4 a = en4[2 * i], b = en4[2 * i + 1];
  float n0 = __int_as_float(a.z), n1 = __int_as_float(b.z);
  *(int2*)&psrc[2 * i] = make_int2(a.x, b.x);
  const float* w10 = wcomp1 + a.y * NB;
  const float* w11 = wcomp1 + b.y * NB;
  const float* w20 = wcomp2 + a.y * NB;
  const float* w21 = wcomp2 + b.y * NB;

  union { _Float16 h[16]; uint4 q[2]; } p;
  #pragma unroll
  for (int bb = 0; bb < NB; bb++) {
    p.h[bb * 2]     = (_Float16)(w10[bb] * n0);
    p.h[bb * 2 + 1] = (_Float16)(w11[bb] * n1);
  }
  *(uint4*)&c1[(size_t)i * 16]     = p.q[0];
  *(uint4*)&c1[(size_t)i * 16 + 8] = p.q[1];
  #pragma unroll
  for (int bb = 0; bb < NB; bb++) {
    p.h[bb * 2]     = (_Float16)(w20[bb] * n0);
    p.h[bb * 2 + 1] = (_Float16)(w21[bb] * n1);
  }
  *(uint4*)&c2[(size_t)i * 16]     = p.q[0];
  *(uint4*)&c2[(size_t)i * 16 + 8] = p.q[1];
}

// ---------------------------------------------------------------------------
// Aggregation: one wave per dst node; edge-pair inner loop with fdot2,
// 4 pairs (8 edges) in flight for deeper memory-level parallelism.
// ---------------------------------------------------------------------------
__global__ __launch_bounds__(256) void k_agg(
    const int* __restrict__ rowst, const int* __restrict__ cnt,
    const int* __restrict__ psrc, const _Float16* __restrict__ cpair,
    const _Float16* __restrict__ hf,
    _Float16* __restrict__ agg, int N)
{
  int v = blockIdx.x * 4 + (threadIdx.x >> 6);
  if (v >= N) return;
  int lane = threadIdx.x & 63;
  const uint_t* hf32 = (const uint_t*)hf;
  const int beg = rowst[v];                    // even by construction
  const int npairs = (cnt[v] + 1) >> 1;
  const uint_t* cp = (const uint_t*)cpair + (size_t)(beg >> 1) * 8;
  const int* ps = psrc + beg;

  float ax[NB] = {}, ay[NB] = {};
  int i = 0;
  for (; i + 4 <= npairs; i += 4) {
    uint_t u[8], lo[4], hi[4];
    #pragma unroll
    for (int q = 0; q < 8; q++)
      u[q] = hf32[(size_t)ps[2*i + q] * 64 + lane];
    #pragma unroll
    for (int q = 0; q < 4; q++) {
      lo[q] = __builtin_amdgcn_perm(u[2*q], u[2*q+1], 0x01000504);
      hi[q] = __builtin_amdgcn_perm(u[2*q], u[2*q+1], 0x03020706);
    }
    #pragma unroll
    for (int b = 0; b < NB; b++) {
      #pragma unroll
      for (int q = 0; q < 4; q++) {
        uint_t cc = cp[(size_t)(i + q) * 8 + b];
        ax[b] = fdot2(cc, lo[q], ax[b]);
        ay[b] = fdot2(cc, hi[q], ay[b]);
      }
    }
  }
  for (; i + 2 <= npairs; i += 2) {
    uint_t u0 = hf32[(size_t)ps[2*i + 0] * 64 + lane];
    uint_t u1 = hf32[(size_t)ps[2*i + 1] * 64 + lane];
    uint_t u2 = hf32[(size_t)ps[2*i + 2] * 64 + lane];
    uint_t u3 = hf32[(size_t)ps[2*i + 3] * 64 + lane];
    uint_t lo01 = __builtin_amdgcn_perm(u0, u1, 0x01000504);
    uint_t hi01 = __builtin_amdgcn_perm(u0, u1, 0x03020706);
    uint_t lo23 = __builtin_amdgcn_perm(u2, u3, 0x01000504);
    uint_t hi23 = __builtin_amdgcn_perm(u2, u3, 0x03020706);
    #pragma unroll
    for (int b = 0; b < NB; b++) {
      uint_t ca = cp[(size_t)i * 8 + b];
      uint_t cb = cp[(size_t)(i + 1) * 8 + b];
      ax[b] = fdot2(ca, lo01, ax[b]);
      ay[b] = fdot2(ca, hi01, ay[b]);
      ax[b] = fdot2(cb, lo23, ax[b]);
      ay[b] = fdot2(cb, hi23, ay[b]);
    }
  }
  if (i < npairs) {
    uint_t u0 = hf32[(size_t)ps[2*i + 0] * 64 + lane];
    uint_t u1 = hf32[(size_t)ps[2*i + 1] * 64 + lane];
    uint_t lo01 = __builtin_amdgcn_perm(u0, u1, 0x01000504);
    uint_t hi01 = __builtin_amdgcn_perm(u0, u1, 0x03020706);
    #pragma unroll
    for (int b = 0; b < NB; b++) {
      uint_t ca = cp[(size_t)i * 8 + b];
      ax[b] = fdot2(ca, lo01, ax[b]);
      ay[b] = fdot2(ca, hi01, ay[b]);
    }
  }

  union { _Float16 e[8]; uint4 q; } p0, p1;
  #pragma unroll
  for (int b = 0; b < NB; b++) { p0.e[b] = (_Float16)ax[b]; p1.e[b] = (_Float16)ay[b]; }
  uint4* dstp = (uint4*)&agg[(size_t)v * 1024 + lane * 16];
  dstp[0] = p0.q;
  dstp[1] = p1.q;
}

// ---------------------------------------------------------------------------
// MFMA GEMM: R9 sync structure, TN=64, but 512 threads / 8 waves.
// Wave wv owns feats [wv*16, wv*16+16) over all 64 nodes: acc f32x4[4].
// Stage: wave wv stages kslot wv with ONE gld_lds (lane = node).
// Grid 782 blocks -> 3 blocks/CU -> 24 waves/CU (75% occupancy) so the
// per-iteration barrier drain overlaps other blocks' compute.
// LDS: 2 x 8KB, [kslot 0..7][node 0..63][8 halves].
// ---------------------------------------------------------------------------
template <int LAYER>
__global__ __launch_bounds__(512) void k_mm(
    const _Float16* __restrict__ agg,   // [N][1024]
    const _Float16* __restrict__ hf,    // [N][128]
    const _Float16* __restrict__ WcA,   // [36][128][32]
    const float* __restrict__ bias,
    float* __restrict__ outf, _Float16* __restrict__ outh, int N)
{
  __shared__ _Float16 sB[2][4096];      // 2 x 8KB

  const int n0   = blockIdx.x * 64;
  const int wv   = threadIdx.x >> 6;    // 0..7
  const int lane = threadIdx.x & 63;
  const int l15  = lane & 15, l4 = lane >> 4;

  int nodeL = n0 + lane; if (nodeL >= N) nodeL = N - 1;   // stage-source clamp

  f32x4 acc[4];
  #pragma unroll
  for (int b = 0; b < 4; b++) acc[b] = (f32x4)0.f;

  const int fbase = wv * 16 + l15;
  const int koff  = l4 * 8;

  auto STAGE = [&](int buf, int t) {
    const _Float16* g;
    if (t < 16) g = &agg[(size_t)nodeL * 1024 + t * 64 + wv * 8];
    else        g = &hf [(size_t)nodeL * DD   + (t - 16) * 64 + wv * 8];
    gld_lds16(g, &sB[buf][wv * 512]);   // kslot wv, dest uniform + lane*16
  };

  auto COMPUTE = [&](int buf, int t) {
    #pragma unroll
    for (int sub = 0; sub < 2; sub++) {
      const int ks = 2 * t + sub;
      half8v af = *(const half8v*)&WcA[((size_t)ks * DD + fbase) * 32 + koff];
      half8v bfr[4];
      #pragma unroll
      for (int nf = 0; nf < 4; nf++)
        bfr[nf] = *(const half8v*)&sB[buf][(sub * 4 + l4) * 512 + (nf * 16 + l15) * 8];
      #pragma unroll
      for (int nf = 0; nf < 4; nf++)
        acc[nf] = __builtin_amdgcn_mfma_f32_16x16x32_f16(af, bfr[nf], acc[nf], 0, 0, 0);
    }
  };

  STAGE(0, 0);
  __syncthreads();
  int cur = 0;
  for (int t = 0; t < 17; t++) {
    STAGE(cur ^ 1, t + 1);
    COMPUTE(cur, t);
    __syncthreads();
    cur ^= 1;
  }
  COMPUTE(cur, 17);

  // C layout: col(=node) = lane&15, row(=feat) = l4*4 + r
  #pragma unroll
  for (int nf = 0; nf < 4; nf++) {
    int n = n0 + nf * 16 + l15;
    if (n >= N) continue;
    int feat = wv * 16 + l4 * 4;
    if (LAYER == 1) {
      union { _Float16 e[4]; uint2 q; } p;
      #pragma unroll
      for (int r = 0; r < 4; r++)
        p.e[r] = (_Float16)fmaxf(acc[nf][r] + bias[feat + r], 0.f);
      *(uint2*)&outh[(size_t)n * DD + feat] = p.q;
    } else {
      float4 o;
      o.x = acc[nf][0] + bias[feat + 0];
      o.y = acc[nf][1] + bias[feat + 1];
      o.z = acc[nf][2] + bias[feat + 2];
      o.w = acc[nf][3] + bias[feat + 3];
      *(float4*)&outf[(size_t)n * DD + feat] = o;
    }
  }
}

extern "C" void kernel_launch(void* const* d_in, const int* in_sizes, int n_in,
                              void* d_out, int out_size, void* d_ws, size_t ws_size,
                              hipStream_t stream)
{
  const int*   h_ids     = (const int*)d_in[0];
  const int*   src       = (const int*)d_in[1];
  const int*   dst       = (const int*)d_in[2];
  const int*   etype     = (const int*)d_in[3];
  const float* norm      = (const float*)d_in[4];
  const float* embedding = (const float*)d_in[5];
  const float* w_comp1   = (const float*)d_in[6];
  const float* bases1    = (const float*)d_in[7];
  const float* loop_w1   = (const float*)d_in[8];
  const float* bias1     = (const float*)d_in[9];
  const float* w_comp2   = (const float*)d_in[10];
  const float* bases2    = (const float*)d_in[11];
  const float* loop_w2   = (const float*)d_in[12];
  const float* bias2     = (const float*)d_in[13];

  const int N = in_sizes[0];
  const int E = in_sizes[1];
  const int S = (E + N) & ~1;           // padded-slot capacity (even)
  const int NPAIR = S >> 1;
  const int NBLK = (N + 255) / 256;     // <= 256 (N <= 65536)

  // ---- workspace carve-up (256B aligned) ----
  char* base = (char*)d_ws;
  size_t off = 0;
  auto alloc = [&](size_t bytes) -> char* {
    char* p = base + off;
    off += (bytes + 255) & ~(size_t)255;
    return p;
  };
  _Float16* agg  = (_Float16*)alloc((size_t)N * 1024 * 2);   // 102.4 MB
  _Float16* hfp  = (_Float16*)alloc((size_t)N * DD * 2);     // 12.8 MB
  _Float16* h1h  = (_Float16*)alloc((size_t)N * DD * 2);     // 12.8 MB
  _Float16* WcA  = (_Float16*)alloc((size_t)2 * 36 * DD * 32 * 2);
  int*      cnt    = (int*)   alloc((size_t)N * 4);          // contiguous with en4
  int4*     en4    = (int4*)  alloc((size_t)S * 16);
  int*      rowst  = (int*)   alloc((size_t)N * 4);
  int*      bsum   = (int*)   alloc(256 * 4);
  int*      boff   = (int*)   alloc(256 * 4);
  int*      slotin = (int*)   alloc((size_t)E * 4);
  int*      psrc   = (int*)   alloc((size_t)S * 4);
  _Float16* c1     = (_Float16*)alloc((size_t)S * 8 * 2);    // ~10.4 MB
  _Float16* c2     = (_Float16*)alloc((size_t)S * 8 * 2);    // ~10.4 MB
  float*    out    = (float*)d_out;

  // ---- build padded CSR by dst (reused by both layers) ----
  // fused zero: cnt (N ints) .. en4 (4S ints) are contiguous
  int zn = (int)(((char*)(en4 + S) - (char*)cnt) / 4);
  k_zero <<<(zn + 255) / 256, 256, 0, stream>>>(cnt, zn);
  k_hist <<<(E + 255) / 256, 256, 0, stream>>>(dst, cnt, slotin, E);
  k_bsum <<<NBLK, 256, 0, stream>>>(cnt, bsum, N);
  k_scanb<<<1, 256, 0, stream>>>(bsum, boff, NBLK);
  k_scan3<<<NBLK, 256, 0, stream>>>(cnt, boff, rowst, N);
  k_place<<<(E + 255) / 256, 256, 0, stream>>>(dst, src, etype, norm,
                                               rowst, slotin, en4, E);
  k_payload_pair<<<(NPAIR + 255) / 256, 256, 0, stream>>>(
      en4, w_comp1, w_comp2, psrc, c1, c2, NPAIR);

  // ---- weights -> fp16 A-coalesced layout ----
  k_prep_w<<<(2 * 36 * DD * 32 + 255) / 256, 256, 0, stream>>>(bases1, loop_w1, bases2, loop_w2, WcA);

  dim3 gmm((N + 63) / 64);
  int gagg = (N + 3) / 4;

  // ---- layer 1 ----
  k_cast<<<(N * (DD / 8) + 255) / 256, 256, 0, stream>>>(embedding, h_ids, hfp, N);
  k_agg<<<gagg, 256, 0, stream>>>(rowst, cnt, psrc, c1, hfp, agg, N);
  k_mm<1><<<gmm, 512, 0, stream>>>(agg, hfp, WcA, bias1, nullptr, h1h, N);

  // ---- layer 2 ----
  k_agg<<<gagg, 256, 0, stream>>>(rowst, cnt, psrc, c2, h1h, agg, N);
  k_mm<2><<<gmm, 512, 0, stream>>>(agg, h1h, WcA + (size_t)36 * DD * 32, bias2, out, nullptr, N);
}